// Round 2
// baseline (487.851 us; speedup 1.0000x reference)
//
#include <hip/hip_runtime.h>
#include <hip/hip_bf16.h>
#include <hip/hip_cooperative_groups.h>
#include <stdint.h>

namespace cg = cooperative_groups;

// Problem constants
#define NB 16       // batch
#define NC 128      // C_in == C_out
#define NK 128      // modes
#define NSP 16384   // spatial N
#define SPLIT 32    // split-K chunks per batch for GEMM1
#define CHUNK 512   // NSP / SPLIT
#define BK 64       // reduction tile for GEMM1

typedef float f32x4 __attribute__((ext_vector_type(4)));
typedef __bf16 bf16x8 __attribute__((ext_vector_type(8)));

__device__ __forceinline__ unsigned short f32_to_bf16(float a) {
  unsigned int u = __float_as_uint(a);
  return (unsigned short)((u + 0x7fffu + ((u >> 16) & 1u)) >> 16);
}

__device__ __forceinline__ unsigned int pack_bf16(float a, float b) {
  unsigned int ua = __float_as_uint(a);
  unsigned int ub = __float_as_uint(b);
  ua = (ua + 0x7fffu + ((ua >> 16) & 1u)) >> 16;
  ub = (ub + 0x7fffu + ((ub >> 16) & 1u)) & 0xffff0000u;
  return ua | ub;
}

// async global->LDS copy, 16 B per lane; LDS dst = base + lane*16 (wave-uniform base)
__device__ __forceinline__ void gl_lds16(const void* g, void* l) {
  __builtin_amdgcn_global_load_lds(
      (const __attribute__((address_space(1))) unsigned int*)g,
      (__attribute__((address_space(3))) unsigned int*)l, 16, 0, 0);
}

// ===========================================================================
// MEGA kernel: stage0 prep -> stage1 GEMM1 split-K -> stage2 reduce ->
// stage3 channel-mix. One cooperative launch, grid 512 x 512 thr =
// exactly 2 blocks/CU co-resident (64 KB LDS, <=128 VGPR via launch_bounds).
// Purpose this round: (a) remove 3 inter-kernel gaps, (b) make the dominant
// cost a SINGLE >100 us dispatch so rocprof top-5 finally shows its counters.
// ===========================================================================
__global__ __launch_bounds__(512, 4)
void mega(const float* __restrict__ x, const float* __restrict__ wb,
          const float* __restrict__ bases, const float* __restrict__ W,
          unsigned short* __restrict__ wbT, unsigned short* __restrict__ bases_bf,
          float* __restrict__ part, float* __restrict__ x_co,
          unsigned short* __restrict__ xhat_bf) {
  cg::grid_group grid = cg::this_grid();
  __shared__ __align__(16) char raw[65536];
  int blk = blockIdx.x;   // 0..511
  int tid = threadIdx.x;  // 0..511
  int gt = blk * 512 + tid;

  // ---- stage 0: wbases transpose (2048 32x32 tiles) + bases f32->bf16 ----
  {
    float(*tile)[32][33] = (float(*)[32][33])raw;
    int h = tid >> 8;  // two 256-thr teams per block
    int vt = tid & 255;
    int tx = vt & 31, ty = vt >> 5;  // ty 0..7
#pragma unroll
    for (int rep = 0; rep < 2; ++rep) {
      int vb = blk * 2 + h + rep * 1024;  // 0..2047
      int kt = (vb & 3) * 32, nt = (vb >> 2) * 32;
#pragma unroll
      for (int i = 0; i < 32; i += 8)
        tile[h][ty + i][tx] = wb[(size_t)(nt + ty + i) * NK + kt + tx];
      __syncthreads();
#pragma unroll
      for (int i = 0; i < 32; i += 8)
        wbT[(size_t)(kt + ty + i) * NSP + nt + tx] =
            f32_to_bf16(tile[h][tx][ty + i]);
      __syncthreads();
    }
    // bases convert: 524288 float4 sites / 262144 threads = 2 each
#pragma unroll
    for (int rep = 0; rep < 2; ++rep) {
      int i = gt + rep * 262144;
      float4 v = ((const float4*)bases)[i];
      uint2 o;
      o.x = pack_bf16(v.x, v.y);
      o.y = pack_bf16(v.z, v.w);
      ((uint2*)bases_bf)[i] = o;
    }
  }
  grid.sync();

  // ---- stage 1: GEMM1 split-K, 2-phase double-buffered (identical to k1 v3)
  {
    int b = blk >> 5;      // / SPLIT
    int chunk = blk & 31;  // % SPLIT
    int n0 = chunk * CHUNK;
    int lane = tid & 63;
    int wave = tid >> 6;        // 0..7
    int cb = (wave & 1) * 64;   // c quadrant
    int kb = (wave >> 1) * 32;  // k-mode block
    int r = lane & 15;
    int q = lane >> 4;

    f32x4 acc[4][2];
#pragma unroll
    for (int t = 0; t < 4; ++t)
#pragma unroll
      for (int u = 0; u < 2; ++u) acc[t][u] = (f32x4){0.f, 0.f, 0.f, 0.f};

    int g = tid & 7;
    int row0 = tid >> 3;  // 0..63, +64 on round 2
    const float* xbase = x + (size_t)(b * NC) * NSP + n0 + g * 8;
    // wbT: instr i covers k-rows 8i..8i+7; lane -> row 8i+(lane>>3).
    // Linear LDS dst slot = lane&7; source slot = (lane&7)^(row&7).
    const unsigned short* wsrc =
        wbT + n0 + (size_t)(lane >> 3) * NSP + ((lane & 7) ^ (lane >> 3)) * 8;

    // LDS carve: A buffers at 0/16K, B buffers at 32K/48K (bytes)
    // prologue: stage it=0 into buffer 0
#pragma unroll
    for (int j = 0; j < 2; ++j) {
      int i = wave * 2 + j;
      gl_lds16(wsrc + (size_t)(i * 8) * NSP, raw + 32768 + i * 1024);
    }
    {
      uint4* wA = (uint4*)raw;
#pragma unroll
      for (int jj = 0; jj < 2; ++jj) {
        int row = row0 + jj * 64;
        const float4* p = (const float4*)(xbase + (size_t)row * NSP);
        float4 a0 = p[0];
        float4 a1 = p[1];
        uint4 u;
        u.x = pack_bf16(a0.x, a0.y);
        u.y = pack_bf16(a0.z, a0.w);
        u.z = pack_bf16(a1.x, a1.y);
        u.w = pack_bf16(a1.z, a1.w);
        wA[g * 128 + row] = u;
      }
    }
    __syncthreads();

    for (int it = 0; it < CHUNK / BK; ++it) {  // 8 iterations
      int cur = it & 1;
      bool pf = (it + 1) < (CHUNK / BK);
      float4 a0[2], a1[2];
      if (pf) {
#pragma unroll
        for (int j = 0; j < 2; ++j) {
          int i = wave * 2 + j;
          gl_lds16(wsrc + (size_t)(i * 8) * NSP + (it + 1) * BK,
                   raw + 32768 + (cur ^ 1) * 16384 + i * 1024);
        }
#pragma unroll
        for (int jj = 0; jj < 2; ++jj) {
          int row = row0 + jj * 64;
          const float4* p =
              (const float4*)(xbase + (size_t)row * NSP + (it + 1) * BK);
          a0[jj] = p[0];
          a1[jj] = p[1];
        }
      }
      const bf16x8* pA = (const bf16x8*)(raw + cur * 16384);
      const char* pB = raw + 32768 + cur * 16384;
#pragma unroll
      for (int s = 0; s < 2; ++s) {
        bf16x8 af[4], bf[2];
        int s4q = s * 4 + q;
#pragma unroll
        for (int t = 0; t < 4; ++t) af[t] = pA[s4q * 128 + cb + 16 * t + r];
#pragma unroll
        for (int u = 0; u < 2; ++u) {
          int rw = kb + 16 * u + r;
          bf[u] = *(const bf16x8*)(pB + rw * 128 + ((s4q ^ (r & 7)) << 4));
        }
#pragma unroll
        for (int t = 0; t < 4; ++t)
#pragma unroll
          for (int u = 0; u < 2; ++u)
            acc[t][u] = __builtin_amdgcn_mfma_f32_16x16x32_bf16(
                af[t], bf[u], acc[t][u], 0, 0, 0);
      }
      if (pf) {
        uint4* wA = (uint4*)(raw + (cur ^ 1) * 16384);
#pragma unroll
        for (int jj = 0; jj < 2; ++jj) {
          int row = row0 + jj * 64;
          uint4 u;
          u.x = pack_bf16(a0[jj].x, a0[jj].y);
          u.y = pack_bf16(a0[jj].z, a0[jj].w);
          u.z = pack_bf16(a1[jj].x, a1[jj].y);
          u.w = pack_bf16(a1[jj].z, a1[jj].w);
          wA[g * 128 + row] = u;
        }
      }
      __syncthreads();
    }

    // C/D layout: col = lane&15, row = (lane>>4)*4 + reg  [m89-verified]
    float* pp = part + (size_t)blk * (NC * NK);
    int rq = q * 4;
#pragma unroll
    for (int t = 0; t < 4; ++t)
#pragma unroll
      for (int u = 0; u < 2; ++u)
#pragma unroll
        for (int v = 0; v < 4; ++v)
          pp[(cb + 16 * t + rq + v) * NK + kb + 16 * u + r] = acc[t][u][v];
  }
  grid.sync();

  // ---- stage 2: reduce SPLIT partials -> x_co. 262144 threads, 1 f32 each.
  {
    int b = gt >> 14;       // / (NC*NK)
    int rk = gt & 16383;
    const float* p = part + (size_t)b * SPLIT * (NC * NK) + rk;
    float s = 0.f;
#pragma unroll
    for (int c = 0; c < SPLIT; ++c) s += p[(size_t)c * (NC * NK)];
    x_co[gt] = s;
  }
  grid.sync();

  // ---- stage 3: per-mode channel mix. gt -> (b, o, k), one output each.
  {
    int b = gt >> 14;
    int o = (gt >> 7) & 127;
    int k = gt & 127;
    const float* xc = x_co + (size_t)b * NC * NK + k;
    const float* wp = W + (size_t)o * NK + k;
    float acc = 0.f;
#pragma unroll 4
    for (int i = 0; i < NC; ++i)
      acc += xc[(size_t)i * NK] * wp[(size_t)i * (NC * NK)];
    xhat_bf[gt] = f32_to_bf16(acc);
  }
}

// ===========================================================================
// Fallback path (non-cooperative), identical numerics — used only if the
// cooperative launch is rejected (e.g. capture incompatibility).
// ===========================================================================
__global__ void k0_prep(const float* __restrict__ wb, unsigned short* __restrict__ wbT,
                        const float* __restrict__ bases, unsigned short* __restrict__ bb) {
  __shared__ float tile[32][33];
  if (blockIdx.x < 2048) {
    int bid = blockIdx.x;
    int kt = (bid & 3) * 32;
    int nt = (bid >> 2) * 32;
    int tx = threadIdx.x & 31;
    int ty = threadIdx.x >> 5;
#pragma unroll
    for (int i = 0; i < 32; i += 8)
      tile[ty + i][tx] = wb[(size_t)(nt + ty + i) * NK + kt + tx];
    __syncthreads();
#pragma unroll
    for (int i = 0; i < 32; i += 8)
      wbT[(size_t)(kt + ty + i) * NSP + nt + tx] = f32_to_bf16(tile[tx][ty + i]);
  } else {
    int i = (blockIdx.x - 2048) * 256 + threadIdx.x;
    float4 v = ((const float4*)bases)[i];
    uint2 o;
    o.x = pack_bf16(v.x, v.y);
    o.y = pack_bf16(v.z, v.w);
    ((uint2*)bb)[i] = o;
  }
}

__global__ __launch_bounds__(512, 4)
void k1_proj(const float* __restrict__ x, const unsigned short* __restrict__ wbT,
             float* __restrict__ part) {
  int blk = blockIdx.x;
  int b = blk >> 5;
  int chunk = blk & 31;
  int n0 = chunk * CHUNK;
  __shared__ unsigned short ldsA[2][8 * 128 * 8];
  __shared__ unsigned short ldsB[2][128 * 64];
  int tid = threadIdx.x;
  int lane = tid & 63;
  int wave = tid >> 6;
  int cb = (wave & 1) * 64;
  int kb = (wave >> 1) * 32;
  int r = lane & 15;
  int q = lane >> 4;
  f32x4 acc[4][2];
#pragma unroll
  for (int t = 0; t < 4; ++t)
#pragma unroll
    for (int u = 0; u < 2; ++u) acc[t][u] = (f32x4){0.f, 0.f, 0.f, 0.f};
  int g = tid & 7;
  int row0 = tid >> 3;
  const float* xbase = x + (size_t)(b * NC) * NSP + n0 + g * 8;
  const unsigned short* wsrc =
      wbT + n0 + (size_t)(lane >> 3) * NSP + ((lane & 7) ^ (lane >> 3)) * 8;
#pragma unroll
  for (int j = 0; j < 2; ++j) {
    int i = wave * 2 + j;
    gl_lds16(wsrc + (size_t)(i * 8) * NSP, (char*)ldsB[0] + i * 1024);
  }
  {
    uint4* wA = (uint4*)ldsA[0];
#pragma unroll
    for (int jj = 0; jj < 2; ++jj) {
      int row = row0 + jj * 64;
      const float4* p = (const float4*)(xbase + (size_t)row * NSP);
      float4 a0 = p[0];
      float4 a1 = p[1];
      uint4 u;
      u.x = pack_bf16(a0.x, a0.y);
      u.y = pack_bf16(a0.z, a0.w);
      u.z = pack_bf16(a1.x, a1.y);
      u.w = pack_bf16(a1.z, a1.w);
      wA[g * 128 + row] = u;
    }
  }
  __syncthreads();
  for (int it = 0; it < CHUNK / BK; ++it) {
    int cur = it & 1;
    bool pf = (it + 1) < (CHUNK / BK);
    float4 a0[2], a1[2];
    if (pf) {
#pragma unroll
      for (int j = 0; j < 2; ++j) {
        int i = wave * 2 + j;
        gl_lds16(wsrc + (size_t)(i * 8) * NSP + (it + 1) * BK,
                 (char*)ldsB[cur ^ 1] + i * 1024);
      }
#pragma unroll
      for (int jj = 0; jj < 2; ++jj) {
        int row = row0 + jj * 64;
        const float4* p = (const float4*)(xbase + (size_t)row * NSP + (it + 1) * BK);
        a0[jj] = p[0];
        a1[jj] = p[1];
      }
    }
    const bf16x8* pA = (const bf16x8*)ldsA[cur];
    const char* pB = (const char*)ldsB[cur];
#pragma unroll
    for (int s = 0; s < 2; ++s) {
      bf16x8 af[4], bf[2];
      int s4q = s * 4 + q;
#pragma unroll
      for (int t = 0; t < 4; ++t) af[t] = pA[s4q * 128 + cb + 16 * t + r];
#pragma unroll
      for (int u = 0; u < 2; ++u) {
        int rw = kb + 16 * u + r;
        bf[u] = *(const bf16x8*)(pB + rw * 128 + ((s4q ^ (r & 7)) << 4));
      }
#pragma unroll
      for (int t = 0; t < 4; ++t)
#pragma unroll
        for (int u = 0; u < 2; ++u)
          acc[t][u] = __builtin_amdgcn_mfma_f32_16x16x32_bf16(af[t], bf[u],
                                                              acc[t][u], 0, 0, 0);
    }
    if (pf) {
      uint4* wA = (uint4*)ldsA[cur ^ 1];
#pragma unroll
      for (int jj = 0; jj < 2; ++jj) {
        int row = row0 + jj * 64;
        uint4 u;
        u.x = pack_bf16(a0[jj].x, a0[jj].y);
        u.y = pack_bf16(a0[jj].z, a0[jj].w);
        u.z = pack_bf16(a1[jj].x, a1[jj].y);
        u.w = pack_bf16(a1[jj].z, a1[jj].w);
        wA[g * 128 + row] = u;
      }
    }
    __syncthreads();
  }
  float* pp = part + (size_t)blk * (NC * NK);
  int rq = q * 4;
#pragma unroll
  for (int t = 0; t < 4; ++t)
#pragma unroll
    for (int u = 0; u < 2; ++u)
#pragma unroll
      for (int v = 0; v < 4; ++v)
        pp[(cb + 16 * t + rq + v) * NK + kb + 16 * u + r] = acc[t][u][v];
}

__global__ __launch_bounds__(256)
void k1b_reduce(const float* __restrict__ part, float* __restrict__ x_co) {
  int idx = blockIdx.x * 256 + threadIdx.x;
  int b = idx >> 13;
  int r2 = idx & 8191;
  const float2* p = (const float2*)(part + (size_t)b * SPLIT * (NC * NK)) + r2;
  float2 s = {0.f, 0.f};
#pragma unroll
  for (int c = 0; c < SPLIT; ++c) {
    float2 v = p[(size_t)c * (NC * NK / 2)];
    s.x += v.x;
    s.y += v.y;
  }
  ((float2*)x_co)[idx] = s;
}

__global__ __launch_bounds__(128)
void k2_mix(const float* __restrict__ x_co, const float* __restrict__ W,
            unsigned short* __restrict__ xhat_bf) {
  int b = blockIdx.x >> 7;
  int o = blockIdx.x & 127;
  int k = threadIdx.x;
  const float* xc = x_co + (size_t)b * NC * NK + k;
  const float* wp = W + (size_t)o * NK + k;
  float acc = 0.f;
#pragma unroll 4
  for (int i = 0; i < NC; ++i)
    acc += xc[(size_t)i * NK] * wp[(size_t)i * (NC * NK)];
  xhat_bf[((size_t)b * NC + o) * NK + k] = f32_to_bf16(acc);
}

// ---------------------------------------------------------------------------
// k3: out (2048 x NSP) = xhat (2048 x 128) @ bases^T — unchanged from r1.
__global__ __launch_bounds__(256, 2)
void k3_recon(const unsigned short* __restrict__ xhat_bf,
              const unsigned short* __restrict__ bases_bf,
              float* __restrict__ out) {
  int blk = blockIdx.x;
  int mo0 = (blk & 15) * 128;
  int n0 = (blk >> 4) * 512;
  __shared__ unsigned short ldsB[2][128 * 128];
  int tid = threadIdx.x;
  int lane = tid & 63;
  int wave = tid >> 6;
  int mb = (wave & 1) * 64;
  int nb = (wave >> 1) * 64;
  int r = lane & 15;
  int q = lane >> 4;

  bf16x8 af[4][4];
#pragma unroll
  for (int t = 0; t < 4; ++t)
#pragma unroll
    for (int s = 0; s < 4; ++s)
      af[t][s] = *(const bf16x8*)(xhat_bf +
                                  (size_t)(mo0 + mb + 16 * t + r) * NK +
                                  s * 32 + q * 8);

  int rlane = lane >> 4;
  int slane = lane & 15;

#pragma unroll
  for (int jj = 0; jj < 8; ++jj) {
    int i = wave * 8 + jj;
    int c = slane ^ (((i & 3) << 2) | rlane);
    gl_lds16(bases_bf + (size_t)(n0 + i * 4 + rlane) * NK + c * 8,
             (char*)ldsB[0] + i * 1024);
  }

  for (int sub = 0; sub < 4; ++sub) {
    __syncthreads();
    int cur = sub & 1;
    if (sub < 3) {
#pragma unroll
      for (int jj = 0; jj < 8; ++jj) {
        int i = wave * 8 + jj;
        int c = slane ^ (((i & 3) << 2) | rlane);
        gl_lds16(bases_bf + (size_t)(n0 + (sub + 1) * 128 + i * 4 + rlane) * NK + c * 8,
                 (char*)ldsB[cur ^ 1] + i * 1024);
      }
    }
    const char* bbuf = (const char*)ldsB[cur];
    f32x4 acc[4][4];
#pragma unroll
    for (int t = 0; t < 4; ++t)
#pragma unroll
      for (int u = 0; u < 4; ++u) acc[t][u] = (f32x4){0.f, 0.f, 0.f, 0.f};
#pragma unroll
    for (int s = 0; s < 4; ++s) {
      bf16x8 bf[4];
      int s4q = s * 4 + q;
#pragma unroll
      for (int u = 0; u < 4; ++u) {
        int rw = nb + 16 * u + r;
        bf[u] = *(const bf16x8*)(bbuf + rw * 256 + ((s4q ^ r) << 4));
      }
#pragma unroll
      for (int t = 0; t < 4; ++t)
#pragma unroll
        for (int u = 0; u < 4; ++u)
          acc[t][u] = __builtin_amdgcn_mfma_f32_16x16x32_bf16(af[t][s], bf[u],
                                                              acc[t][u], 0, 0, 0);
    }
    int rq = q * 4;
#pragma unroll
    for (int t = 0; t < 4; ++t)
#pragma unroll
      for (int u = 0; u < 4; ++u)
#pragma unroll
        for (int v = 0; v < 4; ++v)
          out[(size_t)(mo0 + mb + 16 * t + rq + v) * NSP + n0 + sub * 128 +
              nb + 16 * u + r] = acc[t][u][v];
  }
}

// ---------------------------------------------------------------------------
extern "C" void kernel_launch(void* const* d_in, const int* in_sizes, int n_in,
                              void* d_out, int out_size, void* d_ws, size_t ws_size,
                              hipStream_t stream) {
  const float* x = (const float*)d_in[0];       // (16,128,16384)
  const float* wbases = (const float*)d_in[1];  // (16384,128)
  const float* bases = (const float*)d_in[2];   // (16384,128)
  const float* W = (const float*)d_in[3];       // (128,128,128)
  float* out = (float*)d_out;                   // (16,128,16384)

  char* ws = (char*)d_ws;
  // ws layout (MB): wbT 0..4 | bases_bf 4..8 | part 8..40 | x_co 40..41 | xhat 41..41.5
  if (ws_size < ((size_t)42 << 20)) return;
  unsigned short* wbT = (unsigned short*)(ws);
  unsigned short* bases_bf = (unsigned short*)(ws + ((size_t)4 << 20));
  float* part = (float*)(ws + ((size_t)8 << 20));
  float* x_co = (float*)(ws + ((size_t)40 << 20));
  unsigned short* xhat_bf = (unsigned short*)(ws + ((size_t)41 << 20));

  void* args[] = {(void*)&x, (void*)&wbases, (void*)&bases, (void*)&W,
                  (void*)&wbT, (void*)&bases_bf, (void*)&part,
                  (void*)&x_co, (void*)&xhat_bf};
  hipError_t err = hipLaunchCooperativeKernel((const void*)mega, dim3(512),
                                              dim3(512), args, 0, stream);
  if (err != hipSuccess) {
    // fallback: non-cooperative pipeline, identical numerics
    k0_prep<<<4096, 256, 0, stream>>>(wbases, wbT, bases, bases_bf);
    k1_proj<<<NB * SPLIT, 512, 0, stream>>>(x, wbT, part);
    k1b_reduce<<<512, 256, 0, stream>>>(part, x_co);
    k2_mix<<<NB * NC, 128, 0, stream>>>(x_co, W, xhat_bf);
  }
  k3_recon<<<512, 256, 0, stream>>>(xhat_bf, bases_bf, out);
}

// Round 3
// 360.737 us; speedup vs baseline: 1.3524x; 1.3524x over previous
//
#include <hip/hip_runtime.h>
#include <hip/hip_bf16.h>
#include <stdint.h>

// Problem constants
#define NB 16       // batch
#define NC 128      // C_in == C_out
#define NK 128      // modes
#define NSP 16384   // spatial N
#define SPLIT 32    // split-K chunks per batch for GEMM1
#define CHUNK 512   // NSP / SPLIT
#define BK 64       // reduction tile for GEMM1

typedef float f32x4 __attribute__((ext_vector_type(4)));
typedef __bf16 bf16x8 __attribute__((ext_vector_type(8)));

__device__ __forceinline__ unsigned short f32_to_bf16(float a) {
  unsigned int u = __float_as_uint(a);
  return (unsigned short)((u + 0x7fffu + ((u >> 16) & 1u)) >> 16);
}

__device__ __forceinline__ unsigned int pack_bf16(float a, float b) {
  unsigned int ua = __float_as_uint(a);
  unsigned int ub = __float_as_uint(b);
  ua = (ua + 0x7fffu + ((ua >> 16) & 1u)) >> 16;
  ub = (ub + 0x7fffu + ((ub >> 16) & 1u)) & 0xffff0000u;
  return ua | ub;
}

__device__ __forceinline__ bf16x8 pack8(float4 a0, float4 a1) {
  uint4 u;
  u.x = pack_bf16(a0.x, a0.y);
  u.y = pack_bf16(a0.z, a0.w);
  u.z = pack_bf16(a1.x, a1.y);
  u.w = pack_bf16(a1.z, a1.w);
  return __builtin_bit_cast(bf16x8, u);
}

// ---------------------------------------------------------------------------
// k0: merged prep. Blocks 0..2047: wbases (NSP x NK) f32 -> wbT (NK x NSP) bf16
// (LDS tile transpose). Blocks 2048..4095: bases f32 -> bf16 straight convert.
__global__ void k0_prep(const float* __restrict__ wb, unsigned short* __restrict__ wbT,
                        const float* __restrict__ bases, unsigned short* __restrict__ bb) {
  __shared__ float tile[32][33];
  if (blockIdx.x < 2048) {
    int bid = blockIdx.x;
    int kt = (bid & 3) * 32;
    int nt = (bid >> 2) * 32;
    int tx = threadIdx.x & 31;
    int ty = threadIdx.x >> 5;  // 0..7
#pragma unroll
    for (int i = 0; i < 32; i += 8)
      tile[ty + i][tx] = wb[(size_t)(nt + ty + i) * NK + kt + tx];
    __syncthreads();
#pragma unroll
    for (int i = 0; i < 32; i += 8)
      wbT[(size_t)(kt + ty + i) * NSP + nt + tx] = f32_to_bf16(tile[tx][ty + i]);
  } else {
    int i = (blockIdx.x - 2048) * 256 + threadIdx.x;
    float4 v = ((const float4*)bases)[i];
    uint2 o;
    o.x = pack_bf16(v.x, v.y);
    o.y = pack_bf16(v.z, v.w);
    ((uint2*)bb)[i] = o;
  }
}

// ---------------------------------------------------------------------------
// k1 v4: split-K GEMM1, LDS-FREE / BARRIER-FREE. The contraction axis n is
// contiguous for BOTH operands (x rows f32, wbT rows bf16), so every MFMA
// fragment is a direct 16-32 B global load; q-neighbor lanes complete full
// 128 B lines per instruction. No __syncthreads -> no vmcnt(0) drains; waves
// run free. Grid 1024 (= 4 blocks/CU exactly): b(16) x chunk(32) x khalf(2),
// 256 thr = 4 waves, wave tile 64c x 32k.
// Reuse (A x4 within tile, x-tile x2 across khalf partners, wbT x16 across b)
// is served by L1/L2/L3 (x fits the 256 MB L3; wbT is 4 MB).
__global__ __launch_bounds__(256, 4)
void k1_proj(const float* __restrict__ x, const unsigned short* __restrict__ wbT,
             float* __restrict__ part) {
  int blk = blockIdx.x;
  int khalf = blk >> 9;
  int b = (blk >> 5) & 15;
  int chunk = blk & 31;
  int n0 = chunk * CHUNK;
  int tid = threadIdx.x;
  int lane = tid & 63;
  int wave = tid >> 6;                    // 0..3
  int cb = (wave & 1) * 64;               // c quadrant
  int kb = khalf * 64 + (wave >> 1) * 32; // k-mode block
  int r = lane & 15;
  int q = lane >> 4;

  f32x4 acc[4][2];
#pragma unroll
  for (int t = 0; t < 4; ++t)
#pragma unroll
    for (int u = 0; u < 2; ++u) acc[t][u] = (f32x4){0.f, 0.f, 0.f, 0.f};

  const float* xrow = x + (size_t)(b * NC + cb + r) * NSP + n0;
  const unsigned short* wrow = wbT + (size_t)(kb + r) * NSP + n0;

#pragma unroll 2
  for (int it = 0; it < CHUNK / BK; ++it) {  // 8 iterations
#pragma unroll
    for (int s = 0; s < 2; ++s) {
      int c2 = it * BK + s * 32 + q * 8;
      bf16x8 af[4], bf[2];
#pragma unroll
      for (int t = 0; t < 4; ++t) {
        const float4* p = (const float4*)(xrow + (size_t)t * 16 * NSP + c2);
        af[t] = pack8(p[0], p[1]);
      }
#pragma unroll
      for (int u = 0; u < 2; ++u)
        bf[u] = *(const bf16x8*)(wrow + (size_t)u * 16 * NSP + c2);
#pragma unroll
      for (int t = 0; t < 4; ++t)
#pragma unroll
        for (int u = 0; u < 2; ++u)
          acc[t][u] = __builtin_amdgcn_mfma_f32_16x16x32_bf16(af[t], bf[u],
                                                              acc[t][u], 0, 0, 0);
    }
  }

  // C/D layout: col = lane&15, row = (lane>>4)*4 + reg  [m89-verified]
  float* pp = part + (size_t)(b * SPLIT + chunk) * (NC * NK);
  int rq = q * 4;
#pragma unroll
  for (int t = 0; t < 4; ++t)
#pragma unroll
    for (int u = 0; u < 2; ++u)
#pragma unroll
      for (int v = 0; v < 4; ++v)
        pp[(cb + 16 * t + rq + v) * NK + kb + 16 * u + r] = acc[t][u][v];
}

// ---------------------------------------------------------------------------
// k1b: reduce SPLIT partials -> x_co fp32. float2-vectorized. part is 32 MB,
// freshly written -> L3-resident.
__global__ __launch_bounds__(256)
void k1b_reduce(const float* __restrict__ part, float* __restrict__ x_co) {
  int idx = blockIdx.x * 256 + threadIdx.x;  // 131072 float2 sites
  int b = idx >> 13;                         // / (NC*NK/2)
  int r2 = idx & 8191;
  const float2* p = (const float2*)(part + (size_t)b * SPLIT * (NC * NK)) + r2;
  float2 s = {0.f, 0.f};
#pragma unroll
  for (int c = 0; c < SPLIT; ++c) {
    float2 v = p[(size_t)c * (NC * NK / 2)];
    s.x += v.x;
    s.y += v.y;
  }
  ((float2*)x_co)[idx] = s;
}

// ---------------------------------------------------------------------------
// k2: per-mode channel mix, o-pair per block. Block = (b, o-pair), lanes = k.
// All operands L2/L3-resident (x_co 1 MB, W 8 MB). Fully coalesced.
__global__ __launch_bounds__(128)
void k2_mix(const float* __restrict__ x_co, const float* __restrict__ W,
            unsigned short* __restrict__ xhat_bf) {
  int b = blockIdx.x >> 6;          // 0..15
  int o0 = (blockIdx.x & 63) * 2;   // 0,2,..,126
  int k = threadIdx.x;
  const float* xc = x_co + (size_t)b * NC * NK + k;
  const float* w0 = W + (size_t)o0 * NK + k;
  float a0 = 0.f, a1 = 0.f;
#pragma unroll 4
  for (int i = 0; i < NC; ++i) {
    float v = xc[(size_t)i * NK];
    a0 += v * w0[(size_t)i * (NC * NK)];
    a1 += v * w0[(size_t)i * (NC * NK) + NK];
  }
  size_t base = ((size_t)b * NC + o0) * NK + k;
  xhat_bf[base] = f32_to_bf16(a0);
  xhat_bf[base + NK] = f32_to_bf16(a1);
}

// ---------------------------------------------------------------------------
// k3 v4: out (2048 x NSP) = xhat (2048 x 128) @ bases^T, LDS-FREE /
// BARRIER-FREE. k-modes are contiguous in both xhat and bases_bf rows, so
// A and B fragments are direct 16 B global loads (xhat 512 KB and bases_bf
// 4 MB are L2-resident; per-instr pattern = 16 rows x 64 B). Grid 1024
// (= 4 blocks/CU): 16 mo-tiles x 64 n-chunks of 256; 256 thr = 4 waves,
// wave tile 64m x 64n, 2 sub-tiles of 128 n. Store-BW-bound by design.
__global__ __launch_bounds__(256, 4)
void k3_recon(const unsigned short* __restrict__ xhat_bf,
              const unsigned short* __restrict__ bases_bf,
              float* __restrict__ out) {
  int blk = blockIdx.x;
  int mo0 = (blk & 15) * 128;   // mo inner: consecutive blocks share the bases slice
  int n0 = (blk >> 4) * 256;
  int tid = threadIdx.x;
  int lane = tid & 63;
  int wave = tid >> 6;  // 0..3
  int mb = (wave & 1) * 64;
  int nb = (wave >> 1) * 64;
  int r = lane & 15;
  int q = lane >> 4;
  int rq = q * 4;

  const unsigned short* arow = xhat_bf + (size_t)(mo0 + mb + r) * NK + q * 8;

#pragma unroll
  for (int sub = 0; sub < 2; ++sub) {
    const unsigned short* brow =
        bases_bf + (size_t)(n0 + sub * 128 + nb + r) * NK + q * 8;
    f32x4 acc[4][4];
#pragma unroll
    for (int t = 0; t < 4; ++t)
#pragma unroll
      for (int u = 0; u < 4; ++u) acc[t][u] = (f32x4){0.f, 0.f, 0.f, 0.f};
#pragma unroll
    for (int s = 0; s < 4; ++s) {
      bf16x8 af[4], bf[4];
#pragma unroll
      for (int t = 0; t < 4; ++t)
        af[t] = *(const bf16x8*)(arow + (size_t)t * 16 * NK + s * 32);
#pragma unroll
      for (int u = 0; u < 4; ++u)
        bf[u] = *(const bf16x8*)(brow + (size_t)u * 16 * NK + s * 32);
#pragma unroll
      for (int t = 0; t < 4; ++t)
#pragma unroll
        for (int u = 0; u < 4; ++u)
          acc[t][u] = __builtin_amdgcn_mfma_f32_16x16x32_bf16(af[t], bf[u],
                                                              acc[t][u], 0, 0, 0);
    }
    float* obase = out + (size_t)(mo0 + mb + rq) * NSP + n0 + sub * 128 + nb + r;
#pragma unroll
    for (int t = 0; t < 4; ++t)
#pragma unroll
      for (int u = 0; u < 4; ++u)
#pragma unroll
        for (int v = 0; v < 4; ++v)
          obase[(size_t)(16 * t + v) * NSP + 16 * u] = acc[t][u][v];
  }
}

// ---------------------------------------------------------------------------
extern "C" void kernel_launch(void* const* d_in, const int* in_sizes, int n_in,
                              void* d_out, int out_size, void* d_ws, size_t ws_size,
                              hipStream_t stream) {
  const float* x = (const float*)d_in[0];       // (16,128,16384)
  const float* wbases = (const float*)d_in[1];  // (16384,128)
  const float* bases = (const float*)d_in[2];   // (16384,128)
  const float* W = (const float*)d_in[3];       // (128,128,128)
  float* out = (float*)d_out;                   // (16,128,16384)

  char* ws = (char*)d_ws;
  // ws layout (MB): wbT 0..4 | bases_bf 4..8 | part 8..40 | x_co 40..41 | xhat 41..41.5
  if (ws_size < ((size_t)42 << 20)) return;
  unsigned short* wbT = (unsigned short*)(ws);
  unsigned short* bases_bf = (unsigned short*)(ws + ((size_t)4 << 20));
  float* part = (float*)(ws + ((size_t)8 << 20));
  float* x_co = (float*)(ws + ((size_t)40 << 20));
  unsigned short* xhat_bf = (unsigned short*)(ws + ((size_t)41 << 20));

  k0_prep<<<4096, 256, 0, stream>>>(wbases, wbT, bases, bases_bf);
  k1_proj<<<1024, 256, 0, stream>>>(x, wbT, part);
  k1b_reduce<<<512, 256, 0, stream>>>(part, x_co);
  k2_mix<<<NB * NC / 2, 128, 0, stream>>>(x_co, W, xhat_bf);
  k3_recon<<<1024, 256, 0, stream>>>(xhat_bf, bases_bf, out);
}

// Round 4
// 324.198 us; speedup vs baseline: 1.5048x; 1.1127x over previous
//
#include <hip/hip_runtime.h>
#include <hip/hip_bf16.h>
#include <stdint.h>

// Problem constants
#define NB 16       // batch
#define NC 128      // C_in == C_out
#define NK 128      // modes
#define NSP 16384   // spatial N
#define SPLIT 32    // split-K chunks per batch for GEMM1
#define CHUNK 512   // NSP / SPLIT

typedef float f32x4 __attribute__((ext_vector_type(4)));
typedef __bf16 bf16x8 __attribute__((ext_vector_type(8)));

__device__ __forceinline__ unsigned short f32_to_bf16(float a) {
  unsigned int u = __float_as_uint(a);
  return (unsigned short)((u + 0x7fffu + ((u >> 16) & 1u)) >> 16);
}

__device__ __forceinline__ unsigned int pack_bf16(float a, float b) {
  unsigned int ua = __float_as_uint(a);
  unsigned int ub = __float_as_uint(b);
  ua = (ua + 0x7fffu + ((ua >> 16) & 1u)) >> 16;
  ub = (ub + 0x7fffu + ((ub >> 16) & 1u)) & 0xffff0000u;
  return ua | ub;
}

__device__ __forceinline__ bf16x8 pack8(float4 a0, float4 a1) {
  uint4 u;
  u.x = pack_bf16(a0.x, a0.y);
  u.y = pack_bf16(a0.z, a0.w);
  u.z = pack_bf16(a1.x, a1.y);
  u.w = pack_bf16(a1.z, a1.w);
  return __builtin_bit_cast(bf16x8, u);
}

// async global->LDS copy, 16 B per lane; LDS dst = base + lane*16 (wave-uniform base)
__device__ __forceinline__ void gl_lds16(const void* g, void* l) {
  __builtin_amdgcn_global_load_lds(
      (const __attribute__((address_space(1))) unsigned int*)g,
      (__attribute__((address_space(3))) unsigned int*)l, 16, 0, 0);
}

// ---------------------------------------------------------------------------
// k0: merged prep. Blocks 0..2047: wbases (NSP x NK) f32 -> wbT (NK x NSP) bf16
// (LDS tile transpose). Blocks 2048..4095: bases f32 -> bf16 straight convert.
__global__ void k0_prep(const float* __restrict__ wb, unsigned short* __restrict__ wbT,
                        const float* __restrict__ bases, unsigned short* __restrict__ bb) {
  __shared__ float tile[32][33];
  if (blockIdx.x < 2048) {
    int bid = blockIdx.x;
    int kt = (bid & 3) * 32;
    int nt = (bid >> 2) * 32;
    int tx = threadIdx.x & 31;
    int ty = threadIdx.x >> 5;  // 0..7
#pragma unroll
    for (int i = 0; i < 32; i += 8)
      tile[ty + i][tx] = wb[(size_t)(nt + ty + i) * NK + kt + tx];
    __syncthreads();
#pragma unroll
    for (int i = 0; i < 32; i += 8)
      wbT[(size_t)(kt + ty + i) * NSP + nt + tx] = f32_to_bf16(tile[tx][ty + i]);
  } else {
    int i = (blockIdx.x - 2048) * 256 + threadIdx.x;
    float4 v = ((const float4*)bases)[i];
    uint2 o;
    o.x = pack_bf16(v.x, v.y);
    o.y = pack_bf16(v.z, v.w);
    ((uint2*)bb)[i] = o;
  }
}

// ---------------------------------------------------------------------------
// k1 v5: split-K GEMM1, BOTH operands staged via global_load_lds (zero-VGPR
// in-flight loads -> ~20x the memory-level parallelism of register loads,
// which R3 counters showed capped at 2.3 TB/s). 2-phase double buffer:
// stage(it+1) issued BEFORE compute(it); the barrier's structural vmcnt(0)
// drain then lands after a full compute phase.
// Grid 1024 = chunk(32, fastest -> same-chunk blocks on same XCD for wbT L2
// reuse) x (b,chalf); block = 256 thr, 4 waves; output 64c x 128k; x read
// exactly ONCE (c-split, not k-split). BK=32, LDS 2 x 16 KB.
// A (x, f32, 128 B rows) XOR-swizzled via pre-swizzled global source
// (slot ^= row&7); B (wbT bf16, 64 B rows) naturally bank-optimal.
__global__ __launch_bounds__(256, 4)
void k1_proj(const float* __restrict__ x, const unsigned short* __restrict__ wbT,
             float* __restrict__ part) {
  int blk = blockIdx.x;
  int chunk = blk & 31;   // fastest -> blk%8 == chunk%8 (XCD affinity)
  int bc = blk >> 5;      // 0..31
  int b = bc >> 1;
  int chalf = bc & 1;
  int n0 = chunk * CHUNK;
  __shared__ __align__(16) char lds[2][16384];  // per buf: A 0..8K (64r x 128B), B 8K..16K (128r x 64B)
  int tid = threadIdx.x;
  int lane = tid & 63;
  int wave = tid >> 6;        // 0..3
  int cbw = (wave & 1) * 32;  // c sub-block within the 64-row half
  int kbw = (wave >> 1) * 64; // k half
  int r = lane & 15;
  int q = lane >> 4;

  f32x4 acc[2][4];
#pragma unroll
  for (int t = 0; t < 2; ++t)
#pragma unroll
    for (int u = 0; u < 4; ++u) acc[t][u] = (f32x4){0.f, 0.f, 0.f, 0.f};

  // A staging: instr i covers rows 8i..8i+7; lane -> row 8i+(lane>>3),
  // source col slot (16B units) = (lane&7)^(lane>>3)  [inverse swizzle]
  const float* aptr = x + (size_t)(b * NC + chalf * 64 + (lane >> 3)) * NSP +
                      n0 + ((lane & 7) ^ (lane >> 3)) * 4;
  // B staging: instr i covers rows 16i..16i+15; lane -> row 16i+(lane>>2),
  // col slot = lane&3 (no swizzle needed: 64 B rows rotate banks naturally)
  const unsigned short* bptr =
      wbT + (size_t)(lane >> 2) * NSP + n0 + (lane & 3) * 8;

  // ---- prologue: stage it=0 into buffer 0
#pragma unroll
  for (int j = 0; j < 2; ++j) {
    int i = wave * 2 + j;
    gl_lds16(aptr + (size_t)(8 * i) * NSP, lds[0] + i * 1024);
    gl_lds16(bptr + (size_t)(16 * i) * NSP, lds[0] + 8192 + i * 1024);
  }
  __syncthreads();

#pragma unroll 2
  for (int it = 0; it < CHUNK / 32; ++it) {  // 16 steps of K=32
    int cur = it & 1;
    if (it + 1 < CHUNK / 32) {
      // issue next step's staging BEFORE compute (latency hides under MFMA/ds_read)
#pragma unroll
      for (int j = 0; j < 2; ++j) {
        int i = wave * 2 + j;
        gl_lds16(aptr + (size_t)(8 * i) * NSP + (it + 1) * 32,
                 lds[cur ^ 1] + i * 1024);
        gl_lds16(bptr + (size_t)(16 * i) * NSP + (it + 1) * 32,
                 lds[cur ^ 1] + 8192 + i * 1024);
      }
    }
    const char* La = lds[cur];
    const char* Lb = lds[cur] + 8192;
    bf16x8 af[2], bf[4];
#pragma unroll
    for (int t = 0; t < 2; ++t) {
      int rw = cbw + 16 * t + r;
      float4 f0 = *(const float4*)(La + rw * 128 + (((2 * q + 0) ^ (r & 7)) << 4));
      float4 f1 = *(const float4*)(La + rw * 128 + (((2 * q + 1) ^ (r & 7)) << 4));
      af[t] = pack8(f0, f1);
    }
#pragma unroll
    for (int u = 0; u < 4; ++u) {
      int rk = kbw + 16 * u + r;
      bf[u] = *(const bf16x8*)(Lb + rk * 64 + q * 16);
    }
#pragma unroll
    for (int t = 0; t < 2; ++t)
#pragma unroll
      for (int u = 0; u < 4; ++u)
        acc[t][u] = __builtin_amdgcn_mfma_f32_16x16x32_bf16(af[t], bf[u],
                                                            acc[t][u], 0, 0, 0);
    __syncthreads();  // one barrier/step: drains gl_lds for next buffer
  }

  // C/D layout: col = lane&15, row = (lane>>4)*4 + reg  [m89-verified]
  float* pp = part + (size_t)(b * SPLIT + chunk) * (NC * NK);
  int rq = q * 4;
#pragma unroll
  for (int t = 0; t < 2; ++t)
#pragma unroll
    for (int u = 0; u < 4; ++u)
#pragma unroll
      for (int v = 0; v < 4; ++v)
        pp[(chalf * 64 + cbw + 16 * t + rq + v) * NK + kbw + 16 * u + r] =
            acc[t][u][v];
}

// ---------------------------------------------------------------------------
// k1b: reduce SPLIT partials -> x_co fp32. float2-vectorized; 32 independent
// strided loads per thread = good MLP.
__global__ __launch_bounds__(256)
void k1b_reduce(const float* __restrict__ part, float* __restrict__ x_co) {
  int idx = blockIdx.x * 256 + threadIdx.x;  // 131072 float2 sites
  int b = idx >> 13;                         // / (NC*NK/2)
  int r2 = idx & 8191;
  const float2* p = (const float2*)(part + (size_t)b * SPLIT * (NC * NK)) + r2;
  float2 s = {0.f, 0.f};
#pragma unroll
  for (int c = 0; c < SPLIT; ++c) {
    float2 v = p[(size_t)c * (NC * NK / 2)];
    s.x += v.x;
    s.y += v.y;
  }
  ((float2*)x_co)[idx] = s;
}

// ---------------------------------------------------------------------------
// k2: per-mode channel mix, o-pair per block. Block = (b, o-pair), lanes = k.
// All operands L2/L3-resident (x_co 1 MB, W 8 MB). Fully coalesced.
__global__ __launch_bounds__(128)
void k2_mix(const float* __restrict__ x_co, const float* __restrict__ W,
            unsigned short* __restrict__ xhat_bf) {
  int b = blockIdx.x >> 6;          // 0..15
  int o0 = (blockIdx.x & 63) * 2;   // 0,2,..,126
  int k = threadIdx.x;
  const float* xc = x_co + (size_t)b * NC * NK + k;
  const float* w0 = W + (size_t)o0 * NK + k;
  float a0 = 0.f, a1 = 0.f;
#pragma unroll 4
  for (int i = 0; i < NC; ++i) {
    float v = xc[(size_t)i * NK];
    a0 += v * w0[(size_t)i * (NC * NK)];
    a1 += v * w0[(size_t)i * (NC * NK) + NK];
  }
  size_t base = ((size_t)b * NC + o0) * NK + k;
  xhat_bf[base] = f32_to_bf16(a0);
  xhat_bf[base + NK] = f32_to_bf16(a1);
}

// ---------------------------------------------------------------------------
// k3 v4 (unchanged this round; expected to surface in top-5 next round for
// attribution): out = xhat @ bases^T, LDS-free direct-load MFMA.
__global__ __launch_bounds__(256, 4)
void k3_recon(const unsigned short* __restrict__ xhat_bf,
              const unsigned short* __restrict__ bases_bf,
              float* __restrict__ out) {
  int blk = blockIdx.x;
  int mo0 = (blk & 15) * 128;
  int n0 = (blk >> 4) * 256;
  int tid = threadIdx.x;
  int lane = tid & 63;
  int wave = tid >> 6;  // 0..3
  int mb = (wave & 1) * 64;
  int nb = (wave >> 1) * 64;
  int r = lane & 15;
  int q = lane >> 4;
  int rq = q * 4;

  const unsigned short* arow = xhat_bf + (size_t)(mo0 + mb + r) * NK + q * 8;

#pragma unroll
  for (int sub = 0; sub < 2; ++sub) {
    const unsigned short* brow =
        bases_bf + (size_t)(n0 + sub * 128 + nb + r) * NK + q * 8;
    f32x4 acc[4][4];
#pragma unroll
    for (int t = 0; t < 4; ++t)
#pragma unroll
      for (int u = 0; u < 4; ++u) acc[t][u] = (f32x4){0.f, 0.f, 0.f, 0.f};
#pragma unroll
    for (int s = 0; s < 4; ++s) {
      bf16x8 af[4], bf[4];
#pragma unroll
      for (int t = 0; t < 4; ++t)
        af[t] = *(const bf16x8*)(arow + (size_t)t * 16 * NK + s * 32);
#pragma unroll
      for (int u = 0; u < 4; ++u)
        bf[u] = *(const bf16x8*)(brow + (size_t)u * 16 * NK + s * 32);
#pragma unroll
      for (int t = 0; t < 4; ++t)
#pragma unroll
        for (int u = 0; u < 4; ++u)
          acc[t][u] = __builtin_amdgcn_mfma_f32_16x16x32_bf16(af[t], bf[u],
                                                              acc[t][u], 0, 0, 0);
    }
    float* obase = out + (size_t)(mo0 + mb + rq) * NSP + n0 + sub * 128 + nb + r;
#pragma unroll
    for (int t = 0; t < 4; ++t)
#pragma unroll
      for (int u = 0; u < 4; ++u)
#pragma unroll
        for (int v = 0; v < 4; ++v)
          obase[(size_t)(16 * t + v) * NSP + 16 * u] = acc[t][u][v];
  }
}

// ---------------------------------------------------------------------------
extern "C" void kernel_launch(void* const* d_in, const int* in_sizes, int n_in,
                              void* d_out, int out_size, void* d_ws, size_t ws_size,
                              hipStream_t stream) {
  const float* x = (const float*)d_in[0];       // (16,128,16384)
  const float* wbases = (const float*)d_in[1];  // (16384,128)
  const float* bases = (const float*)d_in[2];   // (16384,128)
  const float* W = (const float*)d_in[3];       // (128,128,128)
  float* out = (float*)d_out;                   // (16,128,16384)

  char* ws = (char*)d_ws;
  // ws layout (MB): wbT 0..4 | bases_bf 4..8 | part 8..40 | x_co 40..41 | xhat 41..41.5
  if (ws_size < ((size_t)42 << 20)) return;
  unsigned short* wbT = (unsigned short*)(ws);
  unsigned short* bases_bf = (unsigned short*)(ws + ((size_t)4 << 20));
  float* part = (float*)(ws + ((size_t)8 << 20));
  float* x_co = (float*)(ws + ((size_t)40 << 20));
  unsigned short* xhat_bf = (unsigned short*)(ws + ((size_t)41 << 20));

  k0_prep<<<4096, 256, 0, stream>>>(wbases, wbT, bases, bases_bf);
  k1_proj<<<1024, 256, 0, stream>>>(x, wbT, part);
  k1b_reduce<<<512, 256, 0, stream>>>(part, x_co);
  k2_mix<<<NB * NC / 2, 128, 0, stream>>>(x_co, W, xhat_bf);
  k3_recon<<<1024, 256, 0, stream>>>(xhat_bf, bases_bf, out);
}